// Round 3
// baseline (119.227 us; speedup 1.0000x reference)
//
#include <hip/hip_runtime.h>

// LSTM cell, B=4096, D=H=1024.
//   X = [inputs | h_prev]  (4096 x 2048) bf16   (ws, 16 MB)
//   Wct[g][h][k] = concat(W_g,U_g)^T bf16       (ws, 16 MB)
//   8-phase 256x256 fused GEMM (4 gates x 64 h per block) + LSTM epilogue.
//   R3: MFMA via inline asm with "+a" accumulators (native AGPR accumulate,
//   no accvgpr shuttling), sched_barrier(0) removed (volatile-asm ordering
//   suffices), kk-outer MFMA order (no same-acc back-to-back chains).

typedef __attribute__((ext_vector_type(8))) short bfrag8;   // 8 bf16 (4 VGPRs)
typedef __attribute__((ext_vector_type(4))) float f32x4;    // MFMA accumulator

__device__ __forceinline__ unsigned int f2bf(float f) {
  unsigned int u = __builtin_bit_cast(unsigned int, f);
  unsigned int r = (u + 0x7fffu + ((u >> 16) & 1u)) >> 16;
  return r & 0xffffu;
}

// ---------------- prep X: [inputs | h_prev] -> bf16 (4096 x 2048) ------------
__global__ __launch_bounds__(256) void prep_x(const float* __restrict__ inputs,
                                              const float* __restrict__ h_prev,
                                              unsigned short* __restrict__ X) {
  int idx = blockIdx.x * 256 + threadIdx.x;
  int b  = idx >> 8;
  int k8 = (idx & 255) * 8;
  const float* src = (k8 < 1024) ? (inputs + (size_t)b * 1024 + k8)
                                 : (h_prev + (size_t)b * 1024 + (k8 - 1024));
  float4 v0 = ((const float4*)src)[0];
  float4 v1 = ((const float4*)src)[1];
  uint4 o;
  o.x = f2bf(v0.x) | (f2bf(v0.y) << 16);
  o.y = f2bf(v0.z) | (f2bf(v0.w) << 16);
  o.z = f2bf(v1.x) | (f2bf(v1.y) << 16);
  o.w = f2bf(v1.z) | (f2bf(v1.w) << 16);
  *(uint4*)(X + (size_t)b * 2048 + k8) = o;
}

// ------------- prep W: transpose+cast 8x (1024x1024 f32) -> Wct[g][h][k] -----
__global__ __launch_bounds__(256) void prep_w(
    const float* __restrict__ s0, const float* __restrict__ s1,
    const float* __restrict__ s2, const float* __restrict__ s3,
    const float* __restrict__ s4, const float* __restrict__ s5,
    const float* __restrict__ s6, const float* __restrict__ s7,
    unsigned short* __restrict__ Wct) {
  int blk = blockIdx.x;
  int m = blk >> 8;
  const float* src = (m == 0) ? s0 : (m == 1) ? s1 : (m == 2) ? s2 : (m == 3) ? s3
                   : (m == 4) ? s4 : (m == 5) ? s5 : (m == 6) ? s6 : s7;
  int g = m >> 1, half = m & 1;
  unsigned short* dst = Wct + (size_t)g * 1024 * 2048 + (size_t)half * 1024;
  int t = blk & 255;
  int k0 = (t >> 4) * 64;
  int h0 = (t & 15) * 64;
  __shared__ float lt[64][68];
  int tid = threadIdx.x;
  #pragma unroll
  for (int it = 0; it < 4; ++it) {
    int r  = (tid >> 4) + it * 16;
    int c4 = (tid & 15) * 4;
    float4 v = *(const float4*)(src + (size_t)(k0 + r) * 1024 + h0 + c4);
    lt[r][c4 + 0] = v.x; lt[r][c4 + 1] = v.y; lt[r][c4 + 2] = v.z; lt[r][c4 + 3] = v.w;
  }
  __syncthreads();
  #pragma unroll
  for (int it = 0; it < 4; ++it) {
    int hh  = (tid >> 4) + it * 16;
    int kk4 = (tid & 15) * 4;
    uint2 o;
    o.x = f2bf(lt[kk4 + 0][hh]) | (f2bf(lt[kk4 + 1][hh]) << 16);
    o.y = f2bf(lt[kk4 + 2][hh]) | (f2bf(lt[kk4 + 3][hh]) << 16);
    *(uint2*)(dst + (size_t)(h0 + hh) * 2048 + k0 + kk4) = o;
  }
}

// ---------------- 8-phase fused 4-gate GEMM + LSTM epilogue ------------------
// 512 thr, 8 waves (2M x 4N). BM=256 rows, N-tile = 256 cols = 4 gates x 64 h.
// BK=64, K=2048 -> 32 K-tiles, 2 per iteration, 8 phases each. 128 KiB LDS:
//   A half0: buf0 @0,     buf1 @16384   (rows   0-127 x 64k)
//   A half1: buf0 @32768, buf1 @49152   (rows 128-255)
//   B half0: buf0 @65536, buf1 @81920   (cols   0-127)
//   B half1: buf0 @98304, buf1 @114688  (cols 128-255)
// global_load_lds width 16, linear dest, pre-swizzled source (slot^=(row&7)),
// ds_read applies the same XOR -> conflict-free (2-way == free).

#define FENCE() asm volatile("" ::: "memory")
#define BARRIER() do { FENCE(); __builtin_amdgcn_s_barrier(); FENCE(); } while (0)
#define VMCNT(n) asm volatile("s_waitcnt vmcnt(" #n ")" ::: "memory")
#define LGKM0() asm volatile("s_waitcnt lgkmcnt(0)" ::: "memory")
#define GLOAD16(gp, lp) __builtin_amdgcn_global_load_lds( \
    (const __attribute__((address_space(1))) unsigned int*)(gp), \
    (__attribute__((address_space(3))) unsigned int*)(lp), 16, 0, 0)
#define DSR(dst, addr, off) asm volatile("ds_read_b128 %0, %1 offset:%c2" \
    : "=v"(dst) : "v"(addr), "n"(off))

#define READ_A8(arr, BUF, RB) do { \
  DSR(arr[0], aA0, (BUF)*16384 + (RB)*128 + 0);    \
  DSR(arr[1], aA1, (BUF)*16384 + (RB)*128 + 0);    \
  DSR(arr[2], aA0, (BUF)*16384 + (RB)*128 + 2048); \
  DSR(arr[3], aA1, (BUF)*16384 + (RB)*128 + 2048); \
  DSR(arr[4], aA0, (BUF)*16384 + (RB)*128 + 4096); \
  DSR(arr[5], aA1, (BUF)*16384 + (RB)*128 + 4096); \
  DSR(arr[6], aA0, (BUF)*16384 + (RB)*128 + 6144); \
  DSR(arr[7], aA1, (BUF)*16384 + (RB)*128 + 6144); \
} while (0)

#define READ_B4(arr, BUF, CB) do { \
  DSR(arr[0], aB0, (BUF)*16384 + (CB)*128 + 0);    \
  DSR(arr[1], aB1, (BUF)*16384 + (CB)*128 + 0);    \
  DSR(arr[2], aB0, (BUF)*16384 + (CB)*128 + 2048); \
  DSR(arr[3], aB1, (BUF)*16384 + (CB)*128 + 2048); \
} while (0)

#define STAGE_A(BUF, H, kt) do { int _kb = ((kt) < 32 ? (kt) : 31) * 64; \
  GLOAD16(pA0 + (size_t)(H) * 262144 + _kb, smem + (H)*32768 + (BUF)*16384 + stbase); \
  GLOAD16(pA1 + (size_t)(H) * 262144 + _kb, smem + (H)*32768 + (BUF)*16384 + stbase + 1024); \
} while (0)

#define STAGE_B0(BUF, kt) do { int _kb = ((kt) < 32 ? (kt) : 31) * 64; \
  GLOAD16(pB00 + _kb, smem + 65536 + (BUF)*16384 + stbase); \
  GLOAD16(pB01 + _kb, smem + 65536 + (BUF)*16384 + stbase + 1024); \
} while (0)

#define STAGE_B1(BUF, kt) do { int _kb = ((kt) < 32 ? (kt) : 31) * 64; \
  GLOAD16(pB10 + _kb, smem + 98304 + (BUF)*16384 + stbase); \
  GLOAD16(pB11 + _kb, smem + 98304 + (BUF)*16384 + stbase + 1024); \
} while (0)

// native AGPR accumulate, in-place; volatile => program-ordered after LGKM0()
#define MFMA1(ACC, AF, BF) asm volatile( \
    "v_mfma_f32_16x16x32_bf16 %0, %1, %2, %0" \
    : "+a"(ACC) : "v"(AF), "v"(BF))

#define MFMA16(B4, G0, M0) do { \
  __builtin_amdgcn_s_setprio(1); \
  _Pragma("unroll") for (int kk = 0; kk < 2; ++kk) \
  _Pragma("unroll") for (int ni = 0; ni < 2; ++ni) \
  _Pragma("unroll") for (int mi = 0; mi < 4; ++mi) \
    MFMA1(acc[(G0)+ni][(M0)+mi], a[mi*2+kk], (B4)[ni*2+kk]); \
  __builtin_amdgcn_s_setprio(0); \
} while (0)

__global__ __launch_bounds__(512, 2) void lstm_gemm(
    const unsigned short* __restrict__ X, const unsigned short* __restrict__ Wct,
    const float* __restrict__ c_prev,
    const float* __restrict__ bfv, const float* __restrict__ biv,
    const float* __restrict__ bcv, const float* __restrict__ bov,
    float* __restrict__ out) {
  extern __shared__ __align__(16) char smem[];
  const int tid = threadIdx.x;
  const int lane = tid & 63, w = tid >> 6;
  const int u = lane & 15, q = (lane >> 4) & 3;
  const int wm = w >> 2, wn = w & 3;

  // bijective XCD swizzle (256 % 8 == 0): 2 row-panels per XCD
  const int bid = blockIdx.x;
  const int swz = (bid & 7) * 32 + (bid >> 3);
  const int h0 = (swz & 15) * 64;
  const int row0 = (swz >> 4) * 256;

  const unsigned lds0 = (unsigned)(size_t)((__attribute__((address_space(3))) char*)smem);

  // fragment read addresses (XOR swizzle folded; row&7 == u&7 everywhere)
  const int sw0 = (q ^ (u & 7)) << 4;
  const int sw1 = ((q + 4) ^ (u & 7)) << 4;
  const unsigned aA0 = lds0 + wm * 32768 + u * 128 + sw0;
  const unsigned aA1 = lds0 + wm * 32768 + u * 128 + sw1;
  const unsigned aB0 = lds0 + 65536 + (wn >> 1) * 32768 + ((wn & 1) * 64 + u) * 128 + sw0;
  const unsigned aB1 = lds0 + 65536 + (wn >> 1) * 32768 + ((wn & 1) * 64 + u) * 128 + sw1;

  // staging: wave w loads chunks [w*128, w*128+128), 2 gload16 per half.
  const int stbase = w * 2048 + lane * 16;
  const int rA0 = w * 16 + (lane >> 3), rA1 = rA0 + 8;
  const int ssA = (lane & 7) ^ (rA0 & 7);           // source slot (pre-swizzle)
  const unsigned short* pA0 = X + (size_t)(row0 + rA0) * 2048 + ssA * 8;
  const unsigned short* pA1 = X + (size_t)(row0 + rA1) * 2048 + ssA * 8;
  auto wrow = [&](int C) { return (((C >> 4) & 3) << 10) + h0 + ((C >> 6) << 4) + (C & 15); };
  const unsigned short* pB00 = Wct + (size_t)wrow(rA0) * 2048 + ssA * 8;
  const unsigned short* pB01 = Wct + (size_t)wrow(rA1) * 2048 + ssA * 8;
  const unsigned short* pB10 = Wct + (size_t)wrow(128 + rA0) * 2048 + ssA * 8;
  const unsigned short* pB11 = Wct + (size_t)wrow(128 + rA1) * 2048 + ssA * 8;

  f32x4 acc[4][8];
  #pragma unroll
  for (int g = 0; g < 4; ++g)
    #pragma unroll
    for (int m = 0; m < 8; ++m)
      acc[g][m] = (f32x4){0.f, 0.f, 0.f, 0.f};

  bfrag8 a[8], bh[4], bl0[4], bl1[4];

  // prologue: issue KT0.{B0,B1,A0,A1}, KT1.{B0,B1}; wait KT0 in; preload bl0
  STAGE_B0(0, 0); STAGE_B1(0, 0); STAGE_A(0, 0, 0); STAGE_A(0, 1, 0);
  STAGE_B0(1, 1); STAGE_B1(1, 1);
  VMCNT(4);
  BARRIER();
  READ_B4(bl0, 0, 0);

  #pragma unroll 1
  for (int t = 0; t < 16; ++t) {
    const int kt1 = 2 * t + 1, kt2 = 2 * t + 2, kt3 = 2 * t + 3;
    // PH1: q(lo,lo) of even KT
    READ_A8(a, 0, 0);
    STAGE_A(1, 0, kt1);
    BARRIER(); LGKM0();
    MFMA16(bl0, 0, 0);
    BARRIER();
    // PH2: q(lo,hi)
    READ_B4(bh, 0, 32);
    STAGE_A(1, 1, kt1);
    BARRIER(); LGKM0();
    MFMA16(bh, 2, 0);
    BARRIER();
    // PH3: q(hi,hi)
    READ_A8(a, 0, 64);
    STAGE_B0(0, kt2);
    VMCNT(8);
    BARRIER(); LGKM0();
    MFMA16(bh, 2, 4);
    BARRIER();
    // PH4: q(hi,lo); prefetch odd-KT B-lo
    READ_B4(bl1, 1, 0);
    STAGE_B1(0, kt2);
    VMCNT(4);
    BARRIER(); LGKM0();
    MFMA16(bl0, 0, 4);
    BARRIER();
    // PH5: q(lo,lo) of odd KT
    READ_A8(a, 1, 0);
    STAGE_A(0, 0, kt2);
    BARRIER(); LGKM0();
    MFMA16(bl1, 0, 0);
    BARRIER();
    // PH6: q(lo,hi)
    READ_B4(bh, 1, 32);
    STAGE_A(0, 1, kt2);
    BARRIER(); LGKM0();
    MFMA16(bh, 2, 0);
    BARRIER();
    // PH7: q(hi,hi)
    READ_A8(a, 1, 64);
    STAGE_B0(1, kt3);
    VMCNT(8);
    BARRIER(); LGKM0();
    MFMA16(bh, 2, 4);
    BARRIER();
    // PH8: q(hi,lo); prefetch next even-KT B-lo
    READ_B4(bl0, 0, 0);
    STAGE_B1(1, kt3);
    VMCNT(4);
    BARRIER(); LGKM0();
    MFMA16(bl1, 0, 4);
    BARRIER();
  }
  VMCNT(0);  // drain dangling prefetches before LDS dealloc

  // epilogue: gates -> c_next, h_next.  C/D: col=lane&15, row=q*4+j.
  const int hcol = h0 + wn * 16 + u;
  const float Bgf = bfv[hcol], Bgi = biv[hcol], Bgc = bcv[hcol], Bgo = bov[hcol];
  const int rbw = row0 + wm * 128;
  #pragma unroll
  for (int m = 0; m < 8; ++m) {
    #pragma unroll
    for (int j = 0; j < 4; ++j) {
      const int b = rbw + m * 16 + q * 4 + j;
      float pf = acc[0][m][j] + Bgf;
      float pi = acc[1][m][j] + Bgi;
      float pc = acc[2][m][j] + Bgc;
      float po = acc[3][m][j] + Bgo;
      float fg = 1.f / (1.f + __expf(-pf));
      float ig = 1.f / (1.f + __expf(-pi));
      float ct = 2.f / (1.f + __expf(-2.f * pc)) - 1.f;
      float og = 1.f / (1.f + __expf(-po));
      float cn = fg * c_prev[(size_t)b * 1024 + hcol] + ig * ct;
      float hn = og * (2.f / (1.f + __expf(-2.f * cn)) - 1.f);
      out[(size_t)b * 1024 + hcol] = hn;
      out[(size_t)4096 * 1024 + (size_t)b * 1024 + hcol] = cn;
    }
  }
}

extern "C" void kernel_launch(void* const* d_in, const int* in_sizes, int n_in,
                              void* d_out, int out_size, void* d_ws, size_t ws_size,
                              hipStream_t stream) {
  const float* inputs = (const float*)d_in[0];
  const float* h_prev = (const float*)d_in[1];
  const float* c_prev = (const float*)d_in[2];
  const float* Wf = (const float*)d_in[3];
  const float* Uf = (const float*)d_in[4];
  const float* bf = (const float*)d_in[5];
  const float* Wi = (const float*)d_in[6];
  const float* Ui = (const float*)d_in[7];
  const float* bi = (const float*)d_in[8];
  const float* Wc = (const float*)d_in[9];
  const float* Uc = (const float*)d_in[10];
  const float* bc = (const float*)d_in[11];
  const float* Wo = (const float*)d_in[12];
  const float* Uo = (const float*)d_in[13];
  const float* bo = (const float*)d_in[14];
  float* out = (float*)d_out;

  unsigned short* X   = (unsigned short*)d_ws;                 // 16 MB
  unsigned short* Wct = X + (size_t)4096 * 2048;               // 16 MB

  (void)hipFuncSetAttribute(reinterpret_cast<const void*>(lstm_gemm),
                            hipFuncAttributeMaxDynamicSharedMemorySize, 131072);

  prep_x<<<4096, 256, 0, stream>>>(inputs, h_prev, X);
  prep_w<<<2048, 256, 0, stream>>>(Wf, Uf, Wi, Ui, Wc, Uc, Wo, Uo, Wct);
  lstm_gemm<<<256, 512, 131072, stream>>>(X, Wct, c_prev, bf, bi, bc, bo, out);
}

// Round 4
// 88.370 us; speedup vs baseline: 1.3492x; 1.3492x over previous
//
#include <hip/hip_runtime.h>

// LSTM cell, B=4096, D=H=1024.
//   X = [inputs | h_prev]  (4096 x 2048) bf16   (ws, 16 MB)
//   Wct[g][h][k] = concat(W_g,U_g)^T bf16       (ws, 16 MB)
//   8-phase 256x256 fused GEMM (4 gates x 64 h per block) + LSTM epilogue.
//   R4: accumulators pinned to hard AGPRs a0-a127 (literal-reg asm MFMA +
//   accvgpr_write init + accvgpr_read epilogue, full clobbers). No "+a" value
//   ties (R3's spill storm), no compiler-managed acc (R2's suspected
//   accvgpr shuttling, ~20% VALUBusy).

typedef __attribute__((ext_vector_type(8))) short bfrag8;   // 8 bf16 (4 VGPRs)

__device__ __forceinline__ unsigned int f2bf(float f) {
  unsigned int u = __builtin_bit_cast(unsigned int, f);
  unsigned int r = (u + 0x7fffu + ((u >> 16) & 1u)) >> 16;
  return r & 0xffffu;
}

// ---------------- prep X: [inputs | h_prev] -> bf16 (4096 x 2048) ------------
__global__ __launch_bounds__(256) void prep_x(const float* __restrict__ inputs,
                                              const float* __restrict__ h_prev,
                                              unsigned short* __restrict__ X) {
  int idx = blockIdx.x * 256 + threadIdx.x;
  int b  = idx >> 8;
  int k8 = (idx & 255) * 8;
  const float* src = (k8 < 1024) ? (inputs + (size_t)b * 1024 + k8)
                                 : (h_prev + (size_t)b * 1024 + (k8 - 1024));
  float4 v0 = ((const float4*)src)[0];
  float4 v1 = ((const float4*)src)[1];
  uint4 o;
  o.x = f2bf(v0.x) | (f2bf(v0.y) << 16);
  o.y = f2bf(v0.z) | (f2bf(v0.w) << 16);
  o.z = f2bf(v1.x) | (f2bf(v1.y) << 16);
  o.w = f2bf(v1.z) | (f2bf(v1.w) << 16);
  *(uint4*)(X + (size_t)b * 2048 + k8) = o;
}

// ------------- prep W: transpose+cast 8x (1024x1024 f32) -> Wct[g][h][k] -----
__global__ __launch_bounds__(256) void prep_w(
    const float* __restrict__ s0, const float* __restrict__ s1,
    const float* __restrict__ s2, const float* __restrict__ s3,
    const float* __restrict__ s4, const float* __restrict__ s5,
    const float* __restrict__ s6, const float* __restrict__ s7,
    unsigned short* __restrict__ Wct) {
  int blk = blockIdx.x;
  int m = blk >> 8;
  const float* src = (m == 0) ? s0 : (m == 1) ? s1 : (m == 2) ? s2 : (m == 3) ? s3
                   : (m == 4) ? s4 : (m == 5) ? s5 : (m == 6) ? s6 : s7;
  int g = m >> 1, half = m & 1;
  unsigned short* dst = Wct + (size_t)g * 1024 * 2048 + (size_t)half * 1024;
  int t = blk & 255;
  int k0 = (t >> 4) * 64;
  int h0 = (t & 15) * 64;
  __shared__ float lt[64][68];
  int tid = threadIdx.x;
  #pragma unroll
  for (int it = 0; it < 4; ++it) {
    int r  = (tid >> 4) + it * 16;
    int c4 = (tid & 15) * 4;
    float4 v = *(const float4*)(src + (size_t)(k0 + r) * 1024 + h0 + c4);
    lt[r][c4 + 0] = v.x; lt[r][c4 + 1] = v.y; lt[r][c4 + 2] = v.z; lt[r][c4 + 3] = v.w;
  }
  __syncthreads();
  #pragma unroll
  for (int it = 0; it < 4; ++it) {
    int hh  = (tid >> 4) + it * 16;
    int kk4 = (tid & 15) * 4;
    uint2 o;
    o.x = f2bf(lt[kk4 + 0][hh]) | (f2bf(lt[kk4 + 1][hh]) << 16);
    o.y = f2bf(lt[kk4 + 2][hh]) | (f2bf(lt[kk4 + 3][hh]) << 16);
    *(uint2*)(dst + (size_t)(h0 + hh) * 2048 + k0 + kk4) = o;
  }
}

// ---------------- 8-phase fused 4-gate GEMM + LSTM epilogue ------------------
// Skeleton identical to R2 (verified). acc[g][m] -> AGPR base (g*8+m)*4.

#define FENCE() asm volatile("" ::: "memory")
#define BARRIER() do { FENCE(); __builtin_amdgcn_s_barrier(); FENCE(); } while (0)
#define VMCNT(n) asm volatile("s_waitcnt vmcnt(" #n ")" ::: "memory")
#define LGKM0() asm volatile("s_waitcnt lgkmcnt(0)" ::: "memory")
#define GLOAD16(gp, lp) __builtin_amdgcn_global_load_lds( \
    (const __attribute__((address_space(1))) unsigned int*)(gp), \
    (__attribute__((address_space(3))) unsigned int*)(lp), 16, 0, 0)
#define DSR(dst, addr, off) asm volatile("ds_read_b128 %0, %1 offset:%c2" \
    : "=v"(dst) : "v"(addr), "n"(off))

// full AGPR clobber list (keeps the allocator out of a0-a127)
#define AC "a0","a1","a2","a3","a4","a5","a6","a7","a8","a9","a10","a11","a12","a13","a14","a15", \
 "a16","a17","a18","a19","a20","a21","a22","a23","a24","a25","a26","a27","a28","a29","a30","a31", \
 "a32","a33","a34","a35","a36","a37","a38","a39","a40","a41","a42","a43","a44","a45","a46","a47", \
 "a48","a49","a50","a51","a52","a53","a54","a55","a56","a57","a58","a59","a60","a61","a62","a63", \
 "a64","a65","a66","a67","a68","a69","a70","a71","a72","a73","a74","a75","a76","a77","a78","a79", \
 "a80","a81","a82","a83","a84","a85","a86","a87","a88","a89","a90","a91","a92","a93","a94","a95", \
 "a96","a97","a98","a99","a100","a101","a102","a103","a104","a105","a106","a107","a108","a109","a110","a111", \
 "a112","a113","a114","a115","a116","a117","a118","a119","a120","a121","a122","a123","a124","a125","a126","a127"

#define WZ(n) "v_accvgpr_write_b32 a" #n ", 0\n\t"
#define AINIT() asm volatile( \
 WZ(0)WZ(1)WZ(2)WZ(3)WZ(4)WZ(5)WZ(6)WZ(7)WZ(8)WZ(9)WZ(10)WZ(11)WZ(12)WZ(13)WZ(14)WZ(15) \
 WZ(16)WZ(17)WZ(18)WZ(19)WZ(20)WZ(21)WZ(22)WZ(23)WZ(24)WZ(25)WZ(26)WZ(27)WZ(28)WZ(29)WZ(30)WZ(31) \
 WZ(32)WZ(33)WZ(34)WZ(35)WZ(36)WZ(37)WZ(38)WZ(39)WZ(40)WZ(41)WZ(42)WZ(43)WZ(44)WZ(45)WZ(46)WZ(47) \
 WZ(48)WZ(49)WZ(50)WZ(51)WZ(52)WZ(53)WZ(54)WZ(55)WZ(56)WZ(57)WZ(58)WZ(59)WZ(60)WZ(61)WZ(62)WZ(63) \
 WZ(64)WZ(65)WZ(66)WZ(67)WZ(68)WZ(69)WZ(70)WZ(71)WZ(72)WZ(73)WZ(74)WZ(75)WZ(76)WZ(77)WZ(78)WZ(79) \
 WZ(80)WZ(81)WZ(82)WZ(83)WZ(84)WZ(85)WZ(86)WZ(87)WZ(88)WZ(89)WZ(90)WZ(91)WZ(92)WZ(93)WZ(94)WZ(95) \
 WZ(96)WZ(97)WZ(98)WZ(99)WZ(100)WZ(101)WZ(102)WZ(103)WZ(104)WZ(105)WZ(106)WZ(107)WZ(108)WZ(109)WZ(110)WZ(111) \
 WZ(112)WZ(113)WZ(114)WZ(115)WZ(116)WZ(117)WZ(118)WZ(119)WZ(120)WZ(121)WZ(122)WZ(123)WZ(124)WZ(125)WZ(126)WZ(127) \
 ::: AC)

#define MFMA_ONE(BR, AF, BF) asm volatile( \
    "v_mfma_f32_16x16x32_bf16 a[" BR "], %0, %1, a[" BR "]" \
    :: "v"(AF), "v"(BF) : AC)

// 16-MFMA cluster: acc[(G0+ni)][(M0+mi)] += afr[mi*2+kk] * B4[ni*2+kk]
#define CLUSTER(B4, B00,B01,B02,B03, B10,B11,B12,B13) do { \
  __builtin_amdgcn_s_setprio(1); \
  MFMA_ONE(B00, afr[0], (B4)[0]); MFMA_ONE(B01, afr[2], (B4)[0]); \
  MFMA_ONE(B02, afr[4], (B4)[0]); MFMA_ONE(B03, afr[6], (B4)[0]); \
  MFMA_ONE(B10, afr[0], (B4)[2]); MFMA_ONE(B11, afr[2], (B4)[2]); \
  MFMA_ONE(B12, afr[4], (B4)[2]); MFMA_ONE(B13, afr[6], (B4)[2]); \
  MFMA_ONE(B00, afr[1], (B4)[1]); MFMA_ONE(B01, afr[3], (B4)[1]); \
  MFMA_ONE(B02, afr[5], (B4)[1]); MFMA_ONE(B03, afr[7], (B4)[1]); \
  MFMA_ONE(B10, afr[1], (B4)[3]); MFMA_ONE(B11, afr[3], (B4)[3]); \
  MFMA_ONE(B12, afr[5], (B4)[3]); MFMA_ONE(B13, afr[7], (B4)[3]); \
  __builtin_amdgcn_s_setprio(0); \
} while (0)

// cluster variants: (G0,M0) -> AGPR bases ((G0+ni)*8+M0+mi)*4
#define CL_00(B4) CLUSTER(B4, "0:3","4:7","8:11","12:15", "32:35","36:39","40:43","44:47")
#define CL_20(B4) CLUSTER(B4, "64:67","68:71","72:75","76:79", "96:99","100:103","104:107","108:111")
#define CL_24(B4) CLUSTER(B4, "80:83","84:87","88:91","92:95", "112:115","116:119","120:123","124:127")
#define CL_04(B4) CLUSTER(B4, "16:19","20:23","24:27","28:31", "48:51","52:55","56:59","60:63")

#define READ_A8(arr, BUF, RB) do { \
  DSR(arr[0], aA0, (BUF)*16384 + (RB)*128 + 0);    \
  DSR(arr[1], aA1, (BUF)*16384 + (RB)*128 + 0);    \
  DSR(arr[2], aA0, (BUF)*16384 + (RB)*128 + 2048); \
  DSR(arr[3], aA1, (BUF)*16384 + (RB)*128 + 2048); \
  DSR(arr[4], aA0, (BUF)*16384 + (RB)*128 + 4096); \
  DSR(arr[5], aA1, (BUF)*16384 + (RB)*128 + 4096); \
  DSR(arr[6], aA0, (BUF)*16384 + (RB)*128 + 6144); \
  DSR(arr[7], aA1, (BUF)*16384 + (RB)*128 + 6144); \
} while (0)

#define READ_B4(arr, BUF, CB) do { \
  DSR(arr[0], aB0, (BUF)*16384 + (CB)*128 + 0);    \
  DSR(arr[1], aB1, (BUF)*16384 + (CB)*128 + 0);    \
  DSR(arr[2], aB0, (BUF)*16384 + (CB)*128 + 2048); \
  DSR(arr[3], aB1, (BUF)*16384 + (CB)*128 + 2048); \
} while (0)

#define STAGE_A(BUF, H, kt) do { int _kb = ((kt) < 32 ? (kt) : 31) * 64; \
  GLOAD16(pA0 + (size_t)(H) * 262144 + _kb, smem + (H)*32768 + (BUF)*16384 + stbase); \
  GLOAD16(pA1 + (size_t)(H) * 262144 + _kb, smem + (H)*32768 + (BUF)*16384 + stbase + 1024); \
} while (0)

#define STAGE_B0(BUF, kt) do { int _kb = ((kt) < 32 ? (kt) : 31) * 64; \
  GLOAD16(pB00 + _kb, smem + 65536 + (BUF)*16384 + stbase); \
  GLOAD16(pB01 + _kb, smem + 65536 + (BUF)*16384 + stbase + 1024); \
} while (0)

#define STAGE_B1(BUF, kt) do { int _kb = ((kt) < 32 ? (kt) : 31) * 64; \
  GLOAD16(pB10 + _kb, smem + 98304 + (BUF)*16384 + stbase); \
  GLOAD16(pB11 + _kb, smem + 98304 + (BUF)*16384 + stbase + 1024); \
} while (0)

#define ARD(X, RS) asm volatile("v_accvgpr_read_b32 %0, " RS : "=v"(X))

#define EPI_M(Mi, F0,F1,F2,F3, I0,I1,I2,I3, C0,C1,C2,C3, O0,O1,O2,O3) do { \
  float pf[4], pi[4], pc[4], po[4]; \
  ARD(pf[0],F0); ARD(pf[1],F1); ARD(pf[2],F2); ARD(pf[3],F3); \
  ARD(pi[0],I0); ARD(pi[1],I1); ARD(pi[2],I2); ARD(pi[3],I3); \
  ARD(pc[0],C0); ARD(pc[1],C1); ARD(pc[2],C2); ARD(pc[3],C3); \
  ARD(po[0],O0); ARD(po[1],O1); ARD(po[2],O2); ARD(po[3],O3); \
  _Pragma("unroll") for (int j = 0; j < 4; ++j) { \
    const int b = rbw + (Mi) * 16 + q * 4 + j; \
    float xf = pf[j] + Bgf, xi = pi[j] + Bgi, xc = pc[j] + Bgc, xo = po[j] + Bgo; \
    float fg = 1.f / (1.f + __expf(-xf)); \
    float ig = 1.f / (1.f + __expf(-xi)); \
    float ct = 2.f / (1.f + __expf(-2.f * xc)) - 1.f; \
    float og = 1.f / (1.f + __expf(-xo)); \
    float cn = fg * c_prev[(size_t)b * 1024 + hcol] + ig * ct; \
    float hn = og * (2.f / (1.f + __expf(-2.f * cn)) - 1.f); \
    out[(size_t)b * 1024 + hcol] = hn; \
    out[(size_t)4194304 + (size_t)b * 1024 + hcol] = cn; \
  } \
} while (0)

__global__ __launch_bounds__(512, 2) void lstm_gemm(
    const unsigned short* __restrict__ X, const unsigned short* __restrict__ Wct,
    const float* __restrict__ c_prev,
    const float* __restrict__ bfv, const float* __restrict__ biv,
    const float* __restrict__ bcv, const float* __restrict__ bov,
    float* __restrict__ out) {
  extern __shared__ __align__(16) char smem[];
  const int tid = threadIdx.x;
  const int lane = tid & 63, w = tid >> 6;
  const int u = lane & 15, q = (lane >> 4) & 3;
  const int wm = w >> 2, wn = w & 3;

  const int bid = blockIdx.x;
  const int swz = (bid & 7) * 32 + (bid >> 3);
  const int h0 = (swz & 15) * 64;
  const int row0 = (swz >> 4) * 256;

  const unsigned lds0 = (unsigned)(size_t)((__attribute__((address_space(3))) char*)smem);

  const int sw0 = (q ^ (u & 7)) << 4;
  const int sw1 = ((q + 4) ^ (u & 7)) << 4;
  const unsigned aA0 = lds0 + wm * 32768 + u * 128 + sw0;
  const unsigned aA1 = lds0 + wm * 32768 + u * 128 + sw1;
  const unsigned aB0 = lds0 + 65536 + (wn >> 1) * 32768 + ((wn & 1) * 64 + u) * 128 + sw0;
  const unsigned aB1 = lds0 + 65536 + (wn >> 1) * 32768 + ((wn & 1) * 64 + u) * 128 + sw1;

  const int stbase = w * 2048 + lane * 16;
  const int rA0 = w * 16 + (lane >> 3), rA1 = rA0 + 8;
  const int ssA = (lane & 7) ^ (rA0 & 7);
  const unsigned short* pA0 = X + (size_t)(row0 + rA0) * 2048 + ssA * 8;
  const unsigned short* pA1 = X + (size_t)(row0 + rA1) * 2048 + ssA * 8;
  auto wrow = [&](int C) { return (((C >> 4) & 3) << 10) + h0 + ((C >> 6) << 4) + (C & 15); };
  const unsigned short* pB00 = Wct + (size_t)wrow(rA0) * 2048 + ssA * 8;
  const unsigned short* pB01 = Wct + (size_t)wrow(rA1) * 2048 + ssA * 8;
  const unsigned short* pB10 = Wct + (size_t)wrow(128 + rA0) * 2048 + ssA * 8;
  const unsigned short* pB11 = Wct + (size_t)wrow(128 + rA1) * 2048 + ssA * 8;

  AINIT();

  bfrag8 afr[8], bh[4], bl0[4], bl1[4];

  STAGE_B0(0, 0); STAGE_B1(0, 0); STAGE_A(0, 0, 0); STAGE_A(0, 1, 0);
  STAGE_B0(1, 1); STAGE_B1(1, 1);
  VMCNT(4);
  BARRIER();
  READ_B4(bl0, 0, 0);

  #pragma unroll 1
  for (int t = 0; t < 16; ++t) {
    const int kt1 = 2 * t + 1, kt2 = 2 * t + 2, kt3 = 2 * t + 3;
    // PH1
    READ_A8(afr, 0, 0);
    STAGE_A(1, 0, kt1);
    BARRIER(); LGKM0();
    CL_00(bl0);
    BARRIER();
    // PH2
    READ_B4(bh, 0, 32);
    STAGE_A(1, 1, kt1);
    BARRIER(); LGKM0();
    CL_20(bh);
    BARRIER();
    // PH3
    READ_A8(afr, 0, 64);
    STAGE_B0(0, kt2);
    VMCNT(8);
    BARRIER(); LGKM0();
    CL_24(bh);
    BARRIER();
    // PH4
    READ_B4(bl1, 1, 0);
    STAGE_B1(0, kt2);
    VMCNT(4);
    BARRIER(); LGKM0();
    CL_04(bl0);
    BARRIER();
    // PH5
    READ_A8(afr, 1, 0);
    STAGE_A(0, 0, kt2);
    BARRIER(); LGKM0();
    CL_00(bl1);
    BARRIER();
    // PH6
    READ_B4(bh, 1, 32);
    STAGE_A(0, 1, kt2);
    BARRIER(); LGKM0();
    CL_20(bh);
    BARRIER();
    // PH7
    READ_A8(afr, 1, 64);
    STAGE_B0(1, kt3);
    VMCNT(8);
    BARRIER(); LGKM0();
    CL_24(bh);
    BARRIER();
    // PH8
    READ_B4(bl0, 0, 0);
    STAGE_B1(1, kt3);
    VMCNT(4);
    BARRIER(); LGKM0();
    CL_04(bl1);
    BARRIER();
  }
  VMCNT(0);
  asm volatile("s_nop 7\n\ts_nop 7");   // MFMA -> accvgpr_read hazard guard

  const int hcol = h0 + wn * 16 + u;
  const float Bgf = bfv[hcol], Bgi = biv[hcol], Bgc = bcv[hcol], Bgo = bov[hcol];
  const int rbw = row0 + wm * 128;
  EPI_M(0, "a0","a1","a2","a3",     "a32","a33","a34","a35",
           "a64","a65","a66","a67", "a96","a97","a98","a99");
  EPI_M(1, "a4","a5","a6","a7",     "a36","a37","a38","a39",
           "a68","a69","a70","a71", "a100","a101","a102","a103");
  EPI_M(2, "a8","a9","a10","a11",   "a40","a41","a42","a43",
           "a72","a73","a74","a75", "a104","a105","a106","a107");
  EPI_M(3, "a12","a13","a14","a15", "a44","a45","a46","a47",
           "a76","a77","a78","a79", "a108","a109","a110","a111");
  EPI_M(4, "a16","a17","a18","a19", "a48","a49","a50","a51",
           "a80","a81","a82","a83", "a112","a113","a114","a115");
  EPI_M(5, "a20","a21","a22","a23", "a52","a53","a54","a55",
           "a84","a85","a86","a87", "a116","a117","a118","a119");
  EPI_M(6, "a24","a25","a26","a27", "a56","a57","a58","a59",
           "a88","a89","a90","a91", "a120","a121","a122","a123");
  EPI_M(7, "a28","a29","a30","a31", "a60","a61","a62","a63",
           "a92","a93","a94","a95", "a124","a125","a126","a127");
}

extern "C" void kernel_launch(void* const* d_in, const int* in_sizes, int n_in,
                              void* d_out, int out_size, void* d_ws, size_t ws_size,
                              hipStream_t stream) {
  const float* inputs = (const float*)d_in[0];
  const float* h_prev = (const float*)d_in[1];
  const float* c_prev = (const float*)d_in[2];
  const float* Wf = (const float*)d_in[3];
  const float* Uf = (const float*)d_in[4];
  const float* bf = (const float*)d_in[5];
  const float* Wi = (const float*)d_in[6];
  const float* Ui = (const float*)d_in[7];
  const float* bi = (const float*)d_in[8];
  const float* Wc = (const float*)d_in[9];
  const float* Uc = (const float*)d_in[10];
  const float* bc = (const float*)d_in[11];
  const float* Wo = (const float*)d_in[12];
  const float* Uo = (const float*)d_in[13];
  const float* bo = (const float*)d_in[14];
  float* out = (float*)d_out;

  unsigned short* X   = (unsigned short*)d_ws;                 // 16 MB
  unsigned short* Wct = X + (size_t)4096 * 2048;               // 16 MB

  (void)hipFuncSetAttribute(reinterpret_cast<const void*>(lstm_gemm),
                            hipFuncAttributeMaxDynamicSharedMemorySize, 131072);

  prep_x<<<4096, 256, 0, stream>>>(inputs, h_prev, X);
  prep_w<<<2048, 256, 0, stream>>>(Wf, Uf, Wi, Ui, Wc, Uc, Wo, Uo, Wct);
  lstm_gemm<<<256, 512, 131072, stream>>>(X, Wct, c_prev, bf, bi, bc, bo, out);
}

// Round 5
// 87.334 us; speedup vs baseline: 1.3652x; 1.0119x over previous
//
#include <hip/hip_runtime.h>

// LSTM cell, B=4096, D=H=1024.
//   X = [inputs | h_prev]  (4096 x 2048) bf16   (ws, 16 MB)
//   Wct[g][h][k] = concat(W_g,U_g)^T bf16       (ws, 16 MB)
//   8-phase 256x256 fused GEMM (4 gates x 64 h per block) + LSTM epilogue.
//   R5: single barrier per phase + corrected stage slots / vmcnt drains.
//   Derivation (per-wave loads, 2 per STAGE macro; loop-top outstanding = Bodd(4)):
//     PH1 stage Aodd.h0 ->6 | PH2 stage Aodd.h1 ->8
//     PH3 vmcnt(4): drains Bodd (age 3ph)          -> PH4 may read Bodd
//     PH4 stage Bev+1 (both halves) ->8, vmcnt(4): drains Aodd (age 2ph) -> PH5 reads Aodd
//     PH5 stage Aev+1.h0 ->6 | PH6 stage Aev+1.h1 ->8
//     PH7 vmcnt(4): drains Bev+1 (age 3ph)         -> PH8 reads Bev+1
//     PH8 stage Bodd+1 (both) ->8, vmcnt(4): drains Aev+1 (age 2ph) -> PH1' reads Aev+1
//   Stage-vs-last-read gap = 2 phases for every buffer => one s_barrier/phase is
//   race-free: wave Y's reads of phase P drain before Y reaches B1(P+1); any
//   stage of phase P+2 issues after B1(P+1).

typedef __attribute__((ext_vector_type(8))) short bfrag8;   // 8 bf16 (4 VGPRs)

__device__ __forceinline__ unsigned int f2bf(float f) {
  unsigned int u = __builtin_bit_cast(unsigned int, f);
  unsigned int r = (u + 0x7fffu + ((u >> 16) & 1u)) >> 16;
  return r & 0xffffu;
}

// ---------------- prep X: [inputs | h_prev] -> bf16 (4096 x 2048) ------------
__global__ __launch_bounds__(256) void prep_x(const float* __restrict__ inputs,
                                              const float* __restrict__ h_prev,
                                              unsigned short* __restrict__ X) {
  int idx = blockIdx.x * 256 + threadIdx.x;
  int b  = idx >> 8;
  int k8 = (idx & 255) * 8;
  const float* src = (k8 < 1024) ? (inputs + (size_t)b * 1024 + k8)
                                 : (h_prev + (size_t)b * 1024 + (k8 - 1024));
  float4 v0 = ((const float4*)src)[0];
  float4 v1 = ((const float4*)src)[1];
  uint4 o;
  o.x = f2bf(v0.x) | (f2bf(v0.y) << 16);
  o.y = f2bf(v0.z) | (f2bf(v0.w) << 16);
  o.z = f2bf(v1.x) | (f2bf(v1.y) << 16);
  o.w = f2bf(v1.z) | (f2bf(v1.w) << 16);
  *(uint4*)(X + (size_t)b * 2048 + k8) = o;
}

// ------------- prep W: transpose+cast 8x (1024x1024 f32) -> Wct[g][h][k] -----
__global__ __launch_bounds__(256) void prep_w(
    const float* __restrict__ s0, const float* __restrict__ s1,
    const float* __restrict__ s2, const float* __restrict__ s3,
    const float* __restrict__ s4, const float* __restrict__ s5,
    const float* __restrict__ s6, const float* __restrict__ s7,
    unsigned short* __restrict__ Wct) {
  int blk = blockIdx.x;
  int m = blk >> 8;
  const float* src = (m == 0) ? s0 : (m == 1) ? s1 : (m == 2) ? s2 : (m == 3) ? s3
                   : (m == 4) ? s4 : (m == 5) ? s5 : (m == 6) ? s6 : s7;
  int g = m >> 1, half = m & 1;
  unsigned short* dst = Wct + (size_t)g * 1024 * 2048 + (size_t)half * 1024;
  int t = blk & 255;
  int k0 = (t >> 4) * 64;
  int h0 = (t & 15) * 64;
  __shared__ float lt[64][68];
  int tid = threadIdx.x;
  #pragma unroll
  for (int it = 0; it < 4; ++it) {
    int r  = (tid >> 4) + it * 16;
    int c4 = (tid & 15) * 4;
    float4 v = *(const float4*)(src + (size_t)(k0 + r) * 1024 + h0 + c4);
    lt[r][c4 + 0] = v.x; lt[r][c4 + 1] = v.y; lt[r][c4 + 2] = v.z; lt[r][c4 + 3] = v.w;
  }
  __syncthreads();
  #pragma unroll
  for (int it = 0; it < 4; ++it) {
    int hh  = (tid >> 4) + it * 16;
    int kk4 = (tid & 15) * 4;
    uint2 o;
    o.x = f2bf(lt[kk4 + 0][hh]) | (f2bf(lt[kk4 + 1][hh]) << 16);
    o.y = f2bf(lt[kk4 + 2][hh]) | (f2bf(lt[kk4 + 3][hh]) << 16);
    *(uint2*)(dst + (size_t)(h0 + hh) * 2048 + k0 + kk4) = o;
  }
}

// ---------------- 8-phase fused 4-gate GEMM + LSTM epilogue ------------------

#define FENCE() asm volatile("" ::: "memory")
#define BARRIER() do { FENCE(); __builtin_amdgcn_s_barrier(); FENCE(); } while (0)
#define VMCNT(n) asm volatile("s_waitcnt vmcnt(" #n ")" ::: "memory")
#define LGKM0() asm volatile("s_waitcnt lgkmcnt(0)" ::: "memory")
#define GLOAD16(gp, lp) __builtin_amdgcn_global_load_lds( \
    (const __attribute__((address_space(1))) unsigned int*)(gp), \
    (__attribute__((address_space(3))) unsigned int*)(lp), 16, 0, 0)
#define DSR(dst, addr, off) asm volatile("ds_read_b128 %0, %1 offset:%c2" \
    : "=v"(dst) : "v"(addr), "n"(off))

// full AGPR clobber list (keeps the allocator out of a0-a127)
#define AC "a0","a1","a2","a3","a4","a5","a6","a7","a8","a9","a10","a11","a12","a13","a14","a15", \
 "a16","a17","a18","a19","a20","a21","a22","a23","a24","a25","a26","a27","a28","a29","a30","a31", \
 "a32","a33","a34","a35","a36","a37","a38","a39","a40","a41","a42","a43","a44","a45","a46","a47", \
 "a48","a49","a50","a51","a52","a53","a54","a55","a56","a57","a58","a59","a60","a61","a62","a63", \
 "a64","a65","a66","a67","a68","a69","a70","a71","a72","a73","a74","a75","a76","a77","a78","a79", \
 "a80","a81","a82","a83","a84","a85","a86","a87","a88","a89","a90","a91","a92","a93","a94","a95", \
 "a96","a97","a98","a99","a100","a101","a102","a103","a104","a105","a106","a107","a108","a109","a110","a111", \
 "a112","a113","a114","a115","a116","a117","a118","a119","a120","a121","a122","a123","a124","a125","a126","a127"

#define WZ(n) "v_accvgpr_write_b32 a" #n ", 0\n\t"
#define AINIT() asm volatile( \
 WZ(0)WZ(1)WZ(2)WZ(3)WZ(4)WZ(5)WZ(6)WZ(7)WZ(8)WZ(9)WZ(10)WZ(11)WZ(12)WZ(13)WZ(14)WZ(15) \
 WZ(16)WZ(17)WZ(18)WZ(19)WZ(20)WZ(21)WZ(22)WZ(23)WZ(24)WZ(25)WZ(26)WZ(27)WZ(28)WZ(29)WZ(30)WZ(31) \
 WZ(32)WZ(33)WZ(34)WZ(35)WZ(36)WZ(37)WZ(38)WZ(39)WZ(40)WZ(41)WZ(42)WZ(43)WZ(44)WZ(45)WZ(46)WZ(47) \
 WZ(48)WZ(49)WZ(50)WZ(51)WZ(52)WZ(53)WZ(54)WZ(55)WZ(56)WZ(57)WZ(58)WZ(59)WZ(60)WZ(61)WZ(62)WZ(63) \
 WZ(64)WZ(65)WZ(66)WZ(67)WZ(68)WZ(69)WZ(70)WZ(71)WZ(72)WZ(73)WZ(74)WZ(75)WZ(76)WZ(77)WZ(78)WZ(79) \
 WZ(80)WZ(81)WZ(82)WZ(83)WZ(84)WZ(85)WZ(86)WZ(87)WZ(88)WZ(89)WZ(90)WZ(91)WZ(92)WZ(93)WZ(94)WZ(95) \
 WZ(96)WZ(97)WZ(98)WZ(99)WZ(100)WZ(101)WZ(102)WZ(103)WZ(104)WZ(105)WZ(106)WZ(107)WZ(108)WZ(109)WZ(110)WZ(111) \
 WZ(112)WZ(113)WZ(114)WZ(115)WZ(116)WZ(117)WZ(118)WZ(119)WZ(120)WZ(121)WZ(122)WZ(123)WZ(124)WZ(125)WZ(126)WZ(127) \
 ::: AC)

#define MFMA_ONE(BR, AF, BF) asm volatile( \
    "v_mfma_f32_16x16x32_bf16 a[" BR "], %0, %1, a[" BR "]" \
    :: "v"(AF), "v"(BF) : AC)

// 16-MFMA cluster: acc[(G0+ni)][(M0+mi)] += afr[mi*2+kk] * B4[ni*2+kk]
#define CLUSTER(B4, B00,B01,B02,B03, B10,B11,B12,B13) do { \
  __builtin_amdgcn_s_setprio(1); \
  MFMA_ONE(B00, afr[0], (B4)[0]); MFMA_ONE(B01, afr[2], (B4)[0]); \
  MFMA_ONE(B02, afr[4], (B4)[0]); MFMA_ONE(B03, afr[6], (B4)[0]); \
  MFMA_ONE(B10, afr[0], (B4)[2]); MFMA_ONE(B11, afr[2], (B4)[2]); \
  MFMA_ONE(B12, afr[4], (B4)[2]); MFMA_ONE(B13, afr[6], (B4)[2]); \
  MFMA_ONE(B00, afr[1], (B4)[1]); MFMA_ONE(B01, afr[3], (B4)[1]); \
  MFMA_ONE(B02, afr[5], (B4)[1]); MFMA_ONE(B03, afr[7], (B4)[1]); \
  MFMA_ONE(B10, afr[1], (B4)[3]); MFMA_ONE(B11, afr[3], (B4)[3]); \
  MFMA_ONE(B12, afr[5], (B4)[3]); MFMA_ONE(B13, afr[7], (B4)[3]); \
  __builtin_amdgcn_s_setprio(0); \
} while (0)

#define CL_00(B4) CLUSTER(B4, "0:3","4:7","8:11","12:15", "32:35","36:39","40:43","44:47")
#define CL_20(B4) CLUSTER(B4, "64:67","68:71","72:75","76:79", "96:99","100:103","104:107","108:111")
#define CL_24(B4) CLUSTER(B4, "80:83","84:87","88:91","92:95", "112:115","116:119","120:123","124:127")
#define CL_04(B4) CLUSTER(B4, "16:19","20:23","24:27","28:31", "48:51","52:55","56:59","60:63")

#define READ_A8(arr, BUF, RB) do { \
  DSR(arr[0], aA0, (BUF)*16384 + (RB)*128 + 0);    \
  DSR(arr[1], aA1, (BUF)*16384 + (RB)*128 + 0);    \
  DSR(arr[2], aA0, (BUF)*16384 + (RB)*128 + 2048); \
  DSR(arr[3], aA1, (BUF)*16384 + (RB)*128 + 2048); \
  DSR(arr[4], aA0, (BUF)*16384 + (RB)*128 + 4096); \
  DSR(arr[5], aA1, (BUF)*16384 + (RB)*128 + 4096); \
  DSR(arr[6], aA0, (BUF)*16384 + (RB)*128 + 6144); \
  DSR(arr[7], aA1, (BUF)*16384 + (RB)*128 + 6144); \
} while (0)

#define READ_B4(arr, BUF, CB) do { \
  DSR(arr[0], aB0, (BUF)*16384 + (CB)*128 + 0);    \
  DSR(arr[1], aB1, (BUF)*16384 + (CB)*128 + 0);    \
  DSR(arr[2], aB0, (BUF)*16384 + (CB)*128 + 2048); \
  DSR(arr[3], aB1, (BUF)*16384 + (CB)*128 + 2048); \
} while (0)

#define STAGE_A(BUF, H, kt) do { int _kb = ((kt) < 32 ? (kt) : 31) * 64; \
  GLOAD16(pA0 + (size_t)(H) * 262144 + _kb, smem + (H)*32768 + (BUF)*16384 + stbase); \
  GLOAD16(pA1 + (size_t)(H) * 262144 + _kb, smem + (H)*32768 + (BUF)*16384 + stbase + 1024); \
} while (0)

#define STAGE_B0(BUF, kt) do { int _kb = ((kt) < 32 ? (kt) : 31) * 64; \
  GLOAD16(pB00 + _kb, smem + 65536 + (BUF)*16384 + stbase); \
  GLOAD16(pB01 + _kb, smem + 65536 + (BUF)*16384 + stbase + 1024); \
} while (0)

#define STAGE_B1(BUF, kt) do { int _kb = ((kt) < 32 ? (kt) : 31) * 64; \
  GLOAD16(pB10 + _kb, smem + 98304 + (BUF)*16384 + stbase); \
  GLOAD16(pB11 + _kb, smem + 98304 + (BUF)*16384 + stbase + 1024); \
} while (0)

#define ARD(X, RS) asm volatile("v_accvgpr_read_b32 %0, " RS : "=v"(X))

#define EPI_M(Mi, F0,F1,F2,F3, I0,I1,I2,I3, C0,C1,C2,C3, O0,O1,O2,O3) do { \
  float pf[4], pi[4], pc[4], po[4]; \
  ARD(pf[0],F0); ARD(pf[1],F1); ARD(pf[2],F2); ARD(pf[3],F3); \
  ARD(pi[0],I0); ARD(pi[1],I1); ARD(pi[2],I2); ARD(pi[3],I3); \
  ARD(pc[0],C0); ARD(pc[1],C1); ARD(pc[2],C2); ARD(pc[3],C3); \
  ARD(po[0],O0); ARD(po[1],O1); ARD(po[2],O2); ARD(po[3],O3); \
  _Pragma("unroll") for (int j = 0; j < 4; ++j) { \
    const int b = rbw + (Mi) * 16 + q * 4 + j; \
    float xf = pf[j] + Bgf, xi = pi[j] + Bgi, xc = pc[j] + Bgc, xo = po[j] + Bgo; \
    float fg = 1.f / (1.f + __expf(-xf)); \
    float ig = 1.f / (1.f + __expf(-xi)); \
    float ct = 2.f / (1.f + __expf(-2.f * xc)) - 1.f; \
    float og = 1.f / (1.f + __expf(-xo)); \
    float cn = fg * c_prev[(size_t)b * 1024 + hcol] + ig * ct; \
    float hn = og * (2.f / (1.f + __expf(-2.f * cn)) - 1.f); \
    out[(size_t)b * 1024 + hcol] = hn; \
    out[(size_t)4194304 + (size_t)b * 1024 + hcol] = cn; \
  } \
} while (0)

__global__ __launch_bounds__(512, 2) void lstm_gemm(
    const unsigned short* __restrict__ X, const unsigned short* __restrict__ Wct,
    const float* __restrict__ c_prev,
    const float* __restrict__ bfv, const float* __restrict__ biv,
    const float* __restrict__ bcv, const float* __restrict__ bov,
    float* __restrict__ out) {
  extern __shared__ __align__(16) char smem[];
  const int tid = threadIdx.x;
  const int lane = tid & 63, w = tid >> 6;
  const int u = lane & 15, q = (lane >> 4) & 3;
  const int wm = w >> 2, wn = w & 3;

  const int bid = blockIdx.x;
  const int swz = (bid & 7) * 32 + (bid >> 3);
  const int h0 = (swz & 15) * 64;
  const int row0 = (swz >> 4) * 256;

  const unsigned lds0 = (unsigned)(size_t)((__attribute__((address_space(3))) char*)smem);

  const int sw0 = (q ^ (u & 7)) << 4;
  const int sw1 = ((q + 4) ^ (u & 7)) << 4;
  const unsigned aA0 = lds0 + wm * 32768 + u * 128 + sw0;
  const unsigned aA1 = lds0 + wm * 32768 + u * 128 + sw1;
  const unsigned aB0 = lds0 + 65536 + (wn >> 1) * 32768 + ((wn & 1) * 64 + u) * 128 + sw0;
  const unsigned aB1 = lds0 + 65536 + (wn >> 1) * 32768 + ((wn & 1) * 64 + u) * 128 + sw1;

  const int stbase = w * 2048 + lane * 16;
  const int rA0 = w * 16 + (lane >> 3), rA1 = rA0 + 8;
  const int ssA = (lane & 7) ^ (rA0 & 7);
  const unsigned short* pA0 = X + (size_t)(row0 + rA0) * 2048 + ssA * 8;
  const unsigned short* pA1 = X + (size_t)(row0 + rA1) * 2048 + ssA * 8;
  auto wrow = [&](int C) { return (((C >> 4) & 3) << 10) + h0 + ((C >> 6) << 4) + (C & 15); };
  const unsigned short* pB00 = Wct + (size_t)wrow(rA0) * 2048 + ssA * 8;
  const unsigned short* pB01 = Wct + (size_t)wrow(rA1) * 2048 + ssA * 8;
  const unsigned short* pB10 = Wct + (size_t)wrow(128 + rA0) * 2048 + ssA * 8;
  const unsigned short* pB11 = Wct + (size_t)wrow(128 + rA1) * 2048 + ssA * 8;

  AINIT();

  bfrag8 afr[8], bh[4], bl0[4], bl1[4];

  // prologue: KT0 fully staged + KT1's B issued; leaves exactly [B-odd]=4 in flight
  STAGE_B0(0, 0); STAGE_B1(0, 0); STAGE_A(0, 0, 0); STAGE_A(0, 1, 0);
  STAGE_B0(1, 1); STAGE_B1(1, 1);
  VMCNT(4);
  BARRIER();
  READ_B4(bl0, 0, 0);

  #pragma unroll 1
  for (int t = 0; t < 16; ++t) {
    const int kt1 = 2 * t + 1, kt2 = 2 * t + 2, kt3 = 2 * t + 3;
    // PH1: compute even-KT q(lo,lo); stage A-odd half0
    READ_A8(afr, 0, 0);
    STAGE_A(1, 0, kt1);
    BARRIER(); LGKM0();
    CL_00(bl0);
    // PH2: q(lo,hi); stage A-odd half1
    READ_B4(bh, 0, 32);
    STAGE_A(1, 1, kt1);
    BARRIER(); LGKM0();
    CL_20(bh);
    // PH3: q(hi,hi); drain B-odd (age 3 phases)
    READ_A8(afr, 0, 64);
    VMCNT(4);
    BARRIER(); LGKM0();
    CL_24(bh);
    // PH4: q(hi,lo); read B-odd lo; stage B-even+1 (both); drain A-odd (age 2)
    READ_B4(bl1, 1, 0);
    STAGE_B0(0, kt2);
    STAGE_B1(0, kt2);
    VMCNT(4);
    BARRIER(); LGKM0();
    CL_04(bl0);
    // PH5: odd-KT q(lo,lo); stage A-even+1 half0
    READ_A8(afr, 1, 0);
    STAGE_A(0, 0, kt2);
    BARRIER(); LGKM0();
    CL_00(bl1);
    // PH6: q(lo,hi); stage A-even+1 half1
    READ_B4(bh, 1, 32);
    STAGE_A(0, 1, kt2);
    BARRIER(); LGKM0();
    CL_20(bh);
    // PH7: q(hi,hi); drain B-even+1 (age 3)
    READ_A8(afr, 1, 64);
    VMCNT(4);
    BARRIER(); LGKM0();
    CL_24(bh);
    // PH8: q(hi,lo); read B-even+1 lo; stage B-odd+1 (both); drain A-even+1 (age 2)
    READ_B4(bl0, 0, 0);
    STAGE_B0(1, kt3);
    STAGE_B1(1, kt3);
    VMCNT(4);
    BARRIER(); LGKM0();
    CL_04(bl1);
  }
  VMCNT(0);
  asm volatile("s_nop 7\n\ts_nop 7");   // MFMA -> accvgpr_read hazard guard

  const int hcol = h0 + wn * 16 + u;
  const float Bgf = bfv[hcol], Bgi = biv[hcol], Bgc = bcv[hcol], Bgo = bov[hcol];
  const int rbw = row0 + wm * 128;
  EPI_M(0, "a0","a1","a2","a3",     "a32","a33","a34","a35",
           "a64","a65","a66","a67", "a96","a97","a98","a99");
  EPI_M(1, "a4","a5","a6","a7",     "a36","a37","a38","a39",
           "a68","a69","a70","a71", "a100","a101","a102","a103");
  EPI_M(2, "a8","a9","a10","a11",   "a40","a41","a42","a43",
           "a72","a73","a74","a75", "a104","a105","a106","a107");
  EPI_M(3, "a12","a13","a14","a15", "a44","a45","a46","a47",
           "a76","a77","a78","a79", "a108","a109","a110","a111");
  EPI_M(4, "a16","a17","a18","a19", "a48","a49","a50","a51",
           "a80","a81","a82","a83", "a112","a113","a114","a115");
  EPI_M(5, "a20","a21","a22","a23", "a52","a53","a54","a55",
           "a84","a85","a86","a87", "a116","a117","a118","a119");
  EPI_M(6, "a24","a25","a26","a27", "a56","a57","a58","a59",
           "a88","a89","a90","a91", "a120","a121","a122","a123");
  EPI_M(7, "a28","a29","a30","a31", "a60","a61","a62","a63",
           "a92","a93","a94","a95", "a124","a125","a126","a127");
}

extern "C" void kernel_launch(void* const* d_in, const int* in_sizes, int n_in,
                              void* d_out, int out_size, void* d_ws, size_t ws_size,
                              hipStream_t stream) {
  const float* inputs = (const float*)d_in[0];
  const float* h_prev = (const float*)d_in[1];
  const float* c_prev = (const float*)d_in[2];
  const float* Wf = (const float*)d_in[3];
  const float* Uf = (const float*)d_in[4];
  const float* bf = (const float*)d_in[5];
  const float* Wi = (const float*)d_in[6];
  const float* Ui = (const float*)d_in[7];
  const float* bi = (const float*)d_in[8];
  const float* Wc = (const float*)d_in[9];
  const float* Uc = (const float*)d_in[10];
  const float* bc = (const float*)d_in[11];
  const float* Wo = (const float*)d_in[12];
  const float* Uo = (const float*)d_in[13];
  const float* bo = (const float*)d_in[14];
  float* out = (float*)d_out;

  unsigned short* X   = (unsigned short*)d_ws;                 // 16 MB
  unsigned short* Wct = X + (size_t)4096 * 2048;               // 16 MB

  (void)hipFuncSetAttribute(reinterpret_cast<const void*>(lstm_gemm),
                            hipFuncAttributeMaxDynamicSharedMemorySize, 131072);

  prep_x<<<4096, 256, 0, stream>>>(inputs, h_prev, X);
  prep_w<<<2048, 256, 0, stream>>>(Wf, Uf, Wi, Ui, Wc, Uc, Wo, Uo, Wct);
  lstm_gemm<<<256, 512, 131072, stream>>>(X, Wct, c_prev, bf, bi, bc, bo, out);
}